// Round 12
// baseline (2025.312 us; speedup 1.0000x reference)
//
#include <hip/hip_runtime.h>

#define BS    32
#define MDIM  256
#define NDIM  512
#define ITERS 1000
#define BLK   512
#define ALPHA 0.02f
#define BETA  0.02f

// R12: R4's two-batch software pipeline with the XCD mapping FIXED.
// R4 (correct, slow) scattered each pair's 8 wgs across all 8 XCDs
// (s = bid&7 -> consecutive bids -> round-robin) and paid 5x FETCH +
// inflated visibility latency. R12 remaps: pair p = bid&15, slice
// s = bid>>4 -> the pair's 8 wgs sit at bids {p, p+16, ..., p+112}, all
// == p (mod 8) — the same XCD-equivalence class as R10/R11's proven sets.
// Everything else is R4 verbatim (it PASSED; only mapping changes).
// Mechanism: batch A's store->LLC->detect latency (~2500-2900cy, the floor
// proven by R0-R11) hides under batch B's compute phase and vice versa;
// loop period ~ L + C for TWO batch-iterations instead of L + C for one.
#define NWG   128                  // 16 pairs x 8 slices

// LDS: prologue A-tile [32][ATS=520] + b[32]; iteration reuses floats
// 0..1023 as two w-stage buffers. Padded to 84KB -> 1 wg/CU.
#define ATS      520
#define BT_OFF   (32 * ATS)        // 16640
#define SMEM_FL  21504             // 86016 B

// Exchange slab: [2 parity][BS][512] floats, mantissa-tagged words (low 8
// bits = tag): self-validating (proven protocol). Agent-scope relaxed
// atomics. Coalesced poll: thread polls word tid (4 lines/wave).
#define SLAB_FL  (2 * BS * NDIM)

__device__ __forceinline__ unsigned ld_coh_u32(const void* p) {
  return __hip_atomic_load(reinterpret_cast<const unsigned*>(p),
                           __ATOMIC_RELAXED, __HIP_MEMORY_SCOPE_AGENT);
}
__device__ __forceinline__ void st_coh_u32(void* p, unsigned v) {
  __hip_atomic_store(reinterpret_cast<unsigned*>(p), v,
                     __ATOMIC_RELAXED, __HIP_MEMORY_SCOPE_AGENT);
}
__device__ __forceinline__ unsigned tagf(float v, unsigned tag) {
  return (__float_as_uint(v) & ~0xFFu) | tag;
}

// ---- prologue: build this wave's 8 G-rows (cols {64c+lane}) + c[i_own] ----
__device__ __forceinline__ void build_G(
    const float* __restrict__ Ag, const float* __restrict__ bg,
    float (&Gacc)[8][8], float& cown, float* smem,
    int tid, int lane, int rowbase, int i_own)
{
#pragma unroll
  for (int r = 0; r < 8; ++r)
#pragma unroll
    for (int c = 0; c < 8; ++c) Gacc[r][c] = 0.f;
  cown = 0.f;

  for (int mt = 0; mt < MDIM / 32; ++mt) {
#pragma unroll 4
    for (int q = 0; q < 8; ++q) {
      int f  = q * 512 + tid;            // float4 index in 32x512 tile
      int mm = f >> 7;
      int j  = (f & 127) << 2;
      float4 v = *reinterpret_cast<const float4*>(
          Ag + (size_t)(mt * 32 + mm) * NDIM + j);
      *reinterpret_cast<float4*>(&smem[mm * ATS + j]) = v;
    }
    if (tid < 32) smem[BT_OFF + tid] = bg[mt * 32 + tid];
    __syncthreads();

#pragma unroll 2
    for (int m = 0; m < 32; ++m) {
      const float* row = &smem[m * ATS];
      float4 a0 = *reinterpret_cast<const float4*>(row + rowbase);
      float4 a1 = *reinterpret_cast<const float4*>(row + rowbase + 4);
      float ai[8] = {a0.x,a0.y,a0.z,a0.w, a1.x,a1.y,a1.z,a1.w};
      float aj[8];
#pragma unroll
      for (int c = 0; c < 8; ++c) aj[c] = row[64 * c + lane];  // 2/bank: free
      float bm  = smem[BT_OFF + m];
      float aio = row[i_own];            // 8 addrs x 8-way broadcast: free
#pragma unroll
      for (int r = 0; r < 8; ++r)
#pragma unroll
        for (int c = 0; c < 8; ++c) Gacc[r][c] = fmaf(ai[r], aj[c], Gacc[r][c]);
      cown = fmaf(aio, bm, cown);
    }
    __syncthreads();
  }
}

// ---- one batch-phase: poll w(k) -> stage -> Gw -> t,x update -> store w(k+1)
// Store is the LAST op of the phase: a wave stores tag k+1 only after its
// iter-k LDS reads, so a fast wave passing poll(k+1) proves all wg-mates are
// done reading -> single barrier suffices (R3/R4 proof).
__device__ __forceinline__ void phase(
    const float (&Gacc)[8][8], float cown, float& x, float& t,
    const float* myrd, float* myslot, float* wbuf,
    int tid, int lane, int par, unsigned tag, int npar, unsigned ntag,
    bool do_store)
{
  unsigned q;
  do { q = ld_coh_u32(myrd + par); } while ((q ^ tag) & 0xFFu);
  wbuf[tid] = __uint_as_float(q);
  __syncthreads();

  float wr[8];
#pragma unroll
  for (int c = 0; c < 8; ++c) wr[c] = wbuf[64 * c + lane];   // 2/bank: free

  float S[8];
#pragma unroll
  for (int r = 0; r < 8; ++r) {
    float p = Gacc[r][0] * wr[0];
#pragma unroll
    for (int c = 1; c < 8; ++c) p = fmaf(Gacc[r][c], wr[c], p);
    S[r] = p;
  }

  // value-halving butterfly: after xor 1,2,4 lane holds row (lane&7) summed
  // over its 8-lane group; xor 8,16,32 are single commutative adds -> all 8
  // redundant lanes get bit-identical sums (t stays exactly consistent).
  const bool b0 = lane & 1, b1 = lane & 2, b2 = lane & 4;
  float T[4];
#pragma unroll
  for (int i = 0; i < 4; ++i) {
    float keep = b0 ? S[2*i+1] : S[2*i];
    float send = b0 ? S[2*i]   : S[2*i+1];
    T[i] = keep + __shfl_xor(send, 1);
  }
  float U[2];
#pragma unroll
  for (int i = 0; i < 2; ++i) {
    float keep = b1 ? T[2*i+1] : T[2*i];
    float send = b1 ? T[2*i]   : T[2*i+1];
    U[i] = keep + __shfl_xor(send, 2);
  }
  float Wv;
  {
    float keep = b2 ? U[1] : U[0];
    float send = b2 ? U[0] : U[1];
    Wv = keep + __shfl_xor(send, 4);
  }
  Wv += __shfl_xor(Wv, 8);
  Wv += __shfl_xor(Wv, 16);
  Wv += __shfl_xor(Wv, 32);

  t += BETA * (Wv - cown);                 // t_{k+1}
  float y  = x - ALPHA * t;
  float xn = fmaxf(y - ALPHA, 0.f) - fmaxf(-y - ALPHA, 0.f);  // x_{k+2}
  float wv = 2.f * xn - x;                 // w_{k+1}
  x = xn;
  if (do_store && lane < 8) st_coh_u32(myslot + npar, tagf(wv, ntag));
}

__global__ __launch_bounds__(BLK, 1) void pdhg_kernel(
    const float* __restrict__ A, const float* __restrict__ Bvec,
    float* __restrict__ out, float* __restrict__ slab)
{
  __shared__ float smem[SMEM_FL];
  const int tid    = threadIdx.x;
  const int bid    = blockIdx.x;
  const int p      = bid & 15;           // batch pair 0..15  [R12 remap]
  const int s      = bid >> 4;           // row slice 0..7 (64 rows)
  const int batchA = p;                  // pair (p, p+16): the 8 wgs sit at
  const int batchB = p + 16;             // bids == p (mod 8) -> one XCD class
  const int lane   = tid & 63;
  const int widx   = tid >> 6;           // wave 0..7
  const int rowbase = s * 64 + widx * 8; // wave's 8 G-rows
  const int i_own   = rowbase + (lane & 7);  // lane's row (8-redundant)

  // ================= PROLOGUE: both batches' G rows + c ====================
  float accA[8][8], accB[8][8];
  float cA, cB;
  build_G(A + (size_t)batchA * MDIM * NDIM, Bvec + batchA * MDIM,
          accA, cA, smem, tid, lane, rowbase, i_own);
  build_G(A + (size_t)batchB * MDIM * NDIM, Bvec + batchB * MDIM,
          accB, cB, smem, tid, lane, rowbase, i_own);

  // ================= ITERATION (2-batch pipeline) ==========================
  float xA = 0.f, tA = 0.f, xB = 0.f, tB = 0.f;
  const float* myrdA = slab + batchA * NDIM + tid;
  const float* myrdB = slab + batchB * NDIM + tid;
  float* myslotA = slab + batchA * NDIM + i_own;
  float* myslotB = slab + batchB * NDIM + i_own;

  // head (iter 0): x_1 = sh(0) = 0, w_0 = 0 -> store tag 1, parity 0
  {
    float y = xA - ALPHA * tA;
    float xn = fmaxf(y - ALPHA, 0.f) - fmaxf(-y - ALPHA, 0.f);
    float wv = 2.f * xn - xA; xA = xn;
    if (lane < 8) st_coh_u32(myslotA, tagf(wv, 1u));
  }
  {
    float y = xB - ALPHA * tB;
    float xn = fmaxf(y - ALPHA, 0.f) - fmaxf(-y - ALPHA, 0.f);
    float wv = 2.f * xn - xB; xB = xn;
    if (lane < 8) st_coh_u32(myslotB, tagf(wv, 1u));
  }

  // body j: poll tag j+1 (parity j&1), compute t_{j+1}, x_{j+2},
  // store tag j+2 (parity (j+1)&1). A's store ages through B's phase and
  // the loop backedge; B's through A's phase. j = 0..ITERS-2.
  for (int j = 0; j < ITERS - 1; ++j) {
    const int      par  = (j & 1) * BS * NDIM;
    const unsigned tag  = (unsigned)(j + 1) & 0xFFu;
    const int      npar = ((j + 1) & 1) * BS * NDIM;
    const unsigned ntag = (unsigned)(j + 2) & 0xFFu;
    const bool     ds   = (j < ITERS - 2);
    phase(accA, cA, xA, tA, myrdA, myslotA, smem,       tid, lane,
          par, tag, npar, ntag, ds);
    phase(accB, cB, xB, tB, myrdB, myslotB, smem + 512, tid, lane,
          par, tag, npar, ntag, ds);
  }

  // ---- epilogue: canonical lanes write both x slices ----
  if (lane < 8) {
    out[(size_t)batchA * NDIM + i_own] = xA;
    out[(size_t)batchB * NDIM + i_own] = xB;
  }
}

extern "C" void kernel_launch(void* const* d_in, const int* in_sizes, int n_in,
                              void* d_out, int out_size, void* d_ws, size_t ws_size,
                              hipStream_t stream) {
  const float* A = (const float*)d_in[0];
  const float* b = (const float*)d_in[1];
  float* out  = (float*)d_out;
  float* slab = (float*)d_ws;                    // 128 KiB w-exchange slab

  hipMemsetAsync(d_ws, 0, SLAB_FL * sizeof(float), stream);  // tag 0 != 1,2

  void* args[] = {(void*)&A, (void*)&b, (void*)&out, (void*)&slab};
  hipLaunchCooperativeKernel((const void*)pdhg_kernel, dim3(NWG), dim3(BLK),
                             args, 0, stream);
}